// Round 1
// baseline (285.832 us; speedup 1.0000x reference)
//
#include <hip/hip_runtime.h>

namespace {

constexpr int N = 20;                 // NEIGHBOR_SIZE
constexpr int MATS_PER_WAVE = 3;      // 3 x 20 lanes = 60 of 64
constexpr int WAVES_PER_BLOCK = 4;    // 256 threads
constexpr int MATS_PER_BLOCK = MATS_PER_WAVE * WAVES_PER_BLOCK;  // 12
constexpr float SIGMA_SQ = 1.0f;
constexpr float PHI = 0.5f;
constexpr float TAU = 0.1f;

// One lane owns one column of the (augmented, in-place) Gauss-Jordan tableau.
// Full unroll keeps a[] in registers (compile-time indices only).
__global__ __launch_bounds__(256, 4) void invcov_kernel(
    const float* __restrict__ pos, float* __restrict__ out, int B) {
  const int tid  = threadIdx.x;
  const int wave = tid >> 6;
  const int lane = tid & 63;
  const int g    = lane / N;            // 0..3 (3 == idle tail lanes 60..63)
  const int j    = lane - g * N;        // column index 0..19
  const bool active = (g < MATS_PER_WAVE);
  const int gg   = active ? g : 0;
  const int m    = blockIdx.x * MATS_PER_BLOCK + wave * MATS_PER_WAVE + gg;
  const bool valid = active && (m < B);
  const int mc   = (m < B) ? m : (B - 1);   // clamp for safe loads
  const int base = gg * N;              // wave-lane of this group's column 0

  const float* pm = pos + (size_t)mc * (2 * N);
  const float x = pm[2 * j];
  const float y = pm[2 * j + 1];

  // Build column j of cov: a[i] = sigma^2 exp(-phi * d(i,j)) + tau sigma^2 [i==j]
  float a[N];
#pragma unroll
  for (int i = 0; i < N; ++i) {
    const float dx = pm[2 * i]     - x;
    const float dy = pm[2 * i + 1] - y;
    const float d  = sqrtf(dx * dx + dy * dy);
    float c = SIGMA_SQ * __expf(-PHI * d);
    if (i == j) c += TAU * SIGMA_SQ;
    a[i] = c;
  }

  // In-place Gauss-Jordan inversion, no pivoting (SPD + nugget).
  // Lane j holds column j. Factors A[i][k] live in lane (base+k).
#pragma unroll
  for (int k = 0; k < N; ++k) {
    const float pk = __shfl(a[k], base + k);        // pivot A[k][k]
    const float rp = 1.0f / pk;
    a[k] = (j == k ? 1.0f : a[k]) * rp;             // row k scaled (A[k][k]<-1/p)
#pragma unroll
    for (int i = 0; i < N; ++i) {
      if (i == k) continue;
      const float f   = __shfl(a[i], base + k);     // factor A[i][k]
      const float aik = (j == k) ? 0.0f : a[i];     // A[i][k] <- 0 before update
      a[i] = fmaf(-f, a[k], aik);                   // row_i -= f * row_k
    }
  }

  if (valid) {
    float* om = out + (size_t)m * (N * N);
#pragma unroll
    for (int i = 0; i < N; ++i) om[i * N + j] = a[i];  // lane j writes column j
  }
}

}  // namespace

extern "C" void kernel_launch(void* const* d_in, const int* in_sizes, int n_in,
                              void* d_out, int out_size, void* d_ws, size_t ws_size,
                              hipStream_t stream) {
  const float* pos = (const float*)d_in[0];   // [B, 40] f32
  // d_in[1] (edge_list, int64) is unused by the reference computation.
  float* out = (float*)d_out;                 // [B, 20, 20] f32
  const int B = in_sizes[0] / (2 * N);
  const int blocks = (B + MATS_PER_BLOCK - 1) / MATS_PER_BLOCK;
  invcov_kernel<<<blocks, 256, 0, stream>>>(pos, out, B);
}

// Round 2
// 227.773 us; speedup vs baseline: 1.2549x; 1.2549x over previous
//
#include <hip/hip_runtime.h>

namespace {

constexpr int N = 20;                 // NEIGHBOR_SIZE
constexpr int MATS_PER_WAVE = 3;      // 3 x 20 lanes = 60 of 64
constexpr int WAVES_PER_BLOCK = 4;    // 256 threads
constexpr int MATS_PER_BLOCK = MATS_PER_WAVE * WAVES_PER_BLOCK;  // 12
constexpr float SIGMA_SQ = 1.0f;
constexpr float PHI = 0.5f;
constexpr float TAU = 0.1f;

#define PUBLISH_ROW()                                                     \
  do {                                                                    \
    *(float4*)&Lrow[0]  = make_float4(a[0],  a[1],  a[2],  a[3]);         \
    *(float4*)&Lrow[4]  = make_float4(a[4],  a[5],  a[6],  a[7]);         \
    *(float4*)&Lrow[8]  = make_float4(a[8],  a[9],  a[10], a[11]);        \
    *(float4*)&Lrow[12] = make_float4(a[12], a[13], a[14], a[15]);        \
    *(float4*)&Lrow[16] = make_float4(a[16], a[17], a[18], a[19]);        \
  } while (0)

// Row-parallel in-place Gauss-Jordan inversion (SPD + nugget -> no pivoting).
// Lane j of each 20-lane group owns ROW j in 20 registers. Per step k the
// pivot-row owner publishes its (unscaled) row via LDS; receivers read it as
// 5x ds_read_b128 broadcasts and fold 1/p into the local factor.
__global__ __launch_bounds__(256, 6) void invcov_kernel(
    const float* __restrict__ pos, float* __restrict__ out, int B) {
  // 4 slots per wave: slots 0..2 real groups, slot 3 = dummy for lanes 60..63.
  __shared__ float lds[WAVES_PER_BLOCK][4][N];

  const int tid  = threadIdx.x;
  const int wave = tid >> 6;
  const int lane = tid & 63;
  const int g    = lane / N;            // 0..3
  const int j    = lane - g * N;        // row index 0..19 (lanes 60..63: 0..3)
  const bool active = (g < MATS_PER_WAVE);
  const int m    = blockIdx.x * MATS_PER_BLOCK + wave * MATS_PER_WAVE + (active ? g : 0);
  const bool valid = active && (m < B);
  const int mc   = (m < B) ? m : (B - 1);
  float* Lrow = &lds[wave][g][0];

  const float* pm = pos + (size_t)mc * (2 * N);
  const float x = pm[2 * j];
  const float y = pm[2 * j + 1];
  const float4* pv = (const float4*)pm;

  // Build row j of cov: a[i] = sigma^2 exp(-phi*d(j,i)) + tau*sigma^2 [i==j]
  float a[N];
#pragma unroll
  for (int q = 0; q < N / 2; ++q) {
    const float4 p2 = pv[q];
    {
      constexpr int unused = 0; (void)unused;
      const int i = 2 * q;
      const float dx = p2.x - x, dy = p2.y - y;
      const float d = __builtin_amdgcn_sqrtf(__builtin_fmaf(dx, dx, dy * dy));
      float c = SIGMA_SQ * __expf(-PHI * d);
      if (i == j) c += TAU * SIGMA_SQ;
      a[i] = c;
    }
    {
      const int i = 2 * q + 1;
      const float dx = p2.z - x, dy = p2.w - y;
      const float d = __builtin_amdgcn_sqrtf(__builtin_fmaf(dx, dx, dy * dy));
      float c = SIGMA_SQ * __expf(-PHI * d);
      if (i == j) c += TAU * SIGMA_SQ;
      a[i] = c;
    }
  }

  // Prologue: owner of row 0 publishes it.
  if (j == 0) PUBLISH_ROW();
  asm volatile("s_waitcnt lgkmcnt(0)" ::: "memory");

#pragma unroll
  for (int k = 0; k < N; ++k) {
    // Broadcast-read pivot row k (published at step k-1; unscaled).
    const float4 q0 = *(const float4*)&Lrow[0];
    const float4 q1 = *(const float4*)&Lrow[4];
    const float4 q2 = *(const float4*)&Lrow[8];
    const float4 q3 = *(const float4*)&Lrow[12];
    const float4 q4 = *(const float4*)&Lrow[16];
    const float r[N] = {q0.x, q0.y, q0.z, q0.w, q1.x, q1.y, q1.z, q1.w,
                        q2.x, q2.y, q2.z, q2.w, q3.x, q3.y, q3.z, q3.w,
                        q4.x, q4.y, q4.z, q4.w};
    const float ip = __builtin_amdgcn_rcpf(r[k]);

    if (j == k) {
      // Owner finalizes row k: divide by pivot, diagonal becomes 1/p.
#pragma unroll
      for (int jj = 0; jj < N; ++jj) a[jj] = (jj == k) ? ip : a[jj] * ip;
    } else {
      // row_i -= (A[i][k]/p) * row_k ; A[i][k] <- -A[i][k]/p
      const float f2 = -a[k] * ip;
#pragma unroll
      for (int jj = 0; jj < N; ++jj)
        a[jj] = (jj == k) ? f2 : __builtin_fmaf(f2, r[jj], a[jj]);
    }

    if (k + 1 < N) {
      if (j == k + 1) PUBLISH_ROW();  // publish next pivot row (unscaled)
      asm volatile("s_waitcnt lgkmcnt(0)" ::: "memory");
    }
  }

  if (valid) {
    float* om = out + (size_t)m * (N * N) + j * N;  // lane j writes row j
    *(float4*)&om[0]  = make_float4(a[0],  a[1],  a[2],  a[3]);
    *(float4*)&om[4]  = make_float4(a[4],  a[5],  a[6],  a[7]);
    *(float4*)&om[8]  = make_float4(a[8],  a[9],  a[10], a[11]);
    *(float4*)&om[12] = make_float4(a[12], a[13], a[14], a[15]);
    *(float4*)&om[16] = make_float4(a[16], a[17], a[18], a[19]);
  }
}

}  // namespace

extern "C" void kernel_launch(void* const* d_in, const int* in_sizes, int n_in,
                              void* d_out, int out_size, void* d_ws, size_t ws_size,
                              hipStream_t stream) {
  const float* pos = (const float*)d_in[0];   // [B, 40] f32
  // d_in[1] (edge_list, int64) is unused by the reference computation.
  float* out = (float*)d_out;                 // [B, 20, 20] f32
  const int B = in_sizes[0] / (2 * N);
  const int blocks = (B + MATS_PER_BLOCK - 1) / MATS_PER_BLOCK;
  invcov_kernel<<<blocks, 256, 0, stream>>>(pos, out, B);
}